// Round 12
// baseline (513.159 us; speedup 1.0000x reference)
//
#include <hip/hip_runtime.h>
#include <stdint.h>
#include <math.h>

#define NAG 8192
#define NB  144          // partial row stride: 128 feats + deg col(128) + pad to 9*16
#define BM  64           // M rows per block
#define BK  256          // full K-slice per block, staged once (one barrier)
#define NSPLIT 32        // K splits (fp16 private partials, no atomics)
#define LDA 264          // A LDS row stride in shorts (256 + 8 pad)

typedef __attribute__((ext_vector_type(8))) short short8;
typedef __attribute__((ext_vector_type(4))) float floatx4;

__device__ __forceinline__ float bf2f(unsigned short u) {
    union { uint32_t i; float f; } v; v.i = ((uint32_t)u) << 16; return v.f;
}
__device__ __forceinline__ unsigned short f2bf(float f) {
    union { float f; uint32_t i; } v; v.f = f;
    uint32_t x = v.i;
    return (unsigned short)((x + 0x7FFFu + ((x >> 16) & 1u)) >> 16);  // RNE
}
__device__ __forceinline__ unsigned short f2h(float f) {
    union { _Float16 h; unsigned short u; } v; v.h = (_Float16)f; return v.u;
}
__device__ __forceinline__ float h2f(unsigned short u) {
    union { _Float16 h; unsigned short u; } v; v.u = u; return (float)v.h;
}

// ---------------- Kernel 0: detect float storage dtype from W1 raw bits ----------------
__global__ __launch_bounds__(64) void k0_init(
    int* __restrict__ flag, const unsigned short* __restrict__ W1raw)
{
    int big = 0;
    #pragma unroll
    for (int j = 0; j < 8; ++j) {
        float v = bf2f(W1raw[threadIdx.x * 8 + j]);
        if (!(fabsf(v) <= 1e6f)) big = 1;   // catches huge and NaN (fp32 mantissa noise)
    }
    unsigned long long m = __ballot(big);
    if (threadIdx.x == 0) *flag = (m != 0ull) ? 1 : 0;
}

// ---------------- Kernel 1: h = tanh(obs@W1+b1); write h_f32 and hT_bf16 ----------------
__global__ __launch_bounds__(256) void k1_encode(
    const void* __restrict__ obs,   // [8192][64] fp32 or bf16
    const void* __restrict__ W1,    // [64][128]
    const void* __restrict__ b1,    // [128]
    const int* __restrict__ flag,
    float* __restrict__ h_f32,      // [8192][128]
    unsigned short* __restrict__ hT)// [144][8192] bf16 (row128=ones, 129..143=0)
{
    __shared__ float obs_lds[32][68];
    __shared__ unsigned short ht_lds[128][33];
    const int t = threadIdx.x;
    const int abase = blockIdx.x * 32;
    const bool isf = (*flag != 0);

    {   // stage obs tile 32x64
        int a = t >> 3, c0 = (t & 7) * 8;
        if (isf) {
            const float* p = (const float*)obs;
            #pragma unroll
            for (int j = 0; j < 8; ++j)
                obs_lds[a][c0 + j] = p[(size_t)(abase + a) * 64 + c0 + j];
        } else {
            const unsigned short* p = (const unsigned short*)obs;
            #pragma unroll
            for (int j = 0; j < 8; ++j)
                obs_lds[a][c0 + j] = bf2f(p[(size_t)(abase + a) * 64 + c0 + j]);
        }
    }
    __syncthreads();

    const int o = t & 127;
    const int half = t >> 7;          // wave-uniform
    float acc[16];
    if (isf) {
        const float* Wp = (const float*)W1;
        float bias = ((const float*)b1)[o];
        #pragma unroll
        for (int i = 0; i < 16; ++i) acc[i] = bias;
        for (int k0 = 0; k0 < 64; k0 += 8) {
            float w[8];
            #pragma unroll
            for (int j = 0; j < 8; ++j) w[j] = Wp[(k0 + j) * 128 + o];
            #pragma unroll
            for (int j = 0; j < 8; ++j)
                #pragma unroll
                for (int i = 0; i < 16; ++i)
                    acc[i] = fmaf(obs_lds[half * 16 + i][k0 + j], w[j], acc[i]);
        }
    } else {
        const unsigned short* Wp = (const unsigned short*)W1;
        float bias = bf2f(((const unsigned short*)b1)[o]);
        #pragma unroll
        for (int i = 0; i < 16; ++i) acc[i] = bias;
        for (int k0 = 0; k0 < 64; k0 += 8) {
            float w[8];
            #pragma unroll
            for (int j = 0; j < 8; ++j) w[j] = bf2f(Wp[(k0 + j) * 128 + o]);
            #pragma unroll
            for (int j = 0; j < 8; ++j)
                #pragma unroll
                for (int i = 0; i < 16; ++i)
                    acc[i] = fmaf(obs_lds[half * 16 + i][k0 + j], w[j], acc[i]);
        }
    }
    #pragma unroll
    for (int i = 0; i < 16; ++i) {
        float th = tanhf(acc[i]);
        int a = half * 16 + i;
        h_f32[(size_t)(abase + a) * 128 + o] = th;
        ht_lds[o][a] = f2bf(th);
    }
    __syncthreads();

    for (int p = 0; p < 18; ++p) {
        int n = p * 8 + (t >> 5);
        int a = t & 31;
        unsigned short v;
        if (n < 128)       v = ht_lds[n][a];
        else if (n == 128) v = 0x3F80;     // 1.0 bf16 -> deg column
        else               v = 0;
        hT[(size_t)n * NAG + abase + a] = v;
    }
}

// ---------------- Kernel 2: Cp16[ks] = adj[:, kslice] @ [h|1|0]  (bf16 MFMA) ----------------
// CONTIGUOUS-A staging (rounds 3-11 lesson: every MFMA-layout A access reads 16 rows x
// 128B at 32KB stride per instr -> HBM channel aliasing pins all variants at ~2.7 TB/s).
// Here each staging instr reads ONE adj row, 64 lanes x 16B = 1KB CONTIGUOUS (the pattern
// that hits 6.7 TB/s in fillBuffer), packs {0,1}->bf16, stores LDS. Whole 64x256 K-slice
// staged in one burst -> ONE barrier -> 8 barrier-free windows. B-fragments read DIRECT
// from global (hT=2.4MB, L2-hot; no barrier after -> latency TLP-hidden; LDS holds A only
// -> 33.8KB -> 4 blocks/CU, 16 waves).
__global__ __launch_bounds__(256, 4) void k2_msggemm(
    const int* __restrict__ adj,              // [8192][8192] int32 {0,1}
    const unsigned short* __restrict__ hT,    // [144][8192] bf16
    unsigned short* __restrict__ Cp16)        // [NSPLIT][8192][144] fp16
{
    __shared__ __align__(16) unsigned short Alds[BM * LDA];   // 33,792 B
    const int t = threadIdx.x;
    const int mtile = blockIdx.x & 127;       // 128 M-tiles of 64 rows
    const int ks = blockIdx.x >> 7;           // 32 K-splits of 256
    const int row0 = mtile * BM;
    const int kbeg = ks * 256;

    const int wave = t >> 6, lane = t & 63;
    const int fm = lane & 15, quad = lane >> 4;

    // ---- stage A: wave w, instr n -> row w*16+n, 64 lanes x int4 = 1KB contiguous ----
    {
        const int* src = adj + (size_t)(row0 + wave * 16) * NAG + kbeg + lane * 4;
        #pragma unroll 8
        for (int n = 0; n < 16; ++n) {
            int4 v = *reinterpret_cast<const int4*>(src + (size_t)n * NAG);
            uint32_t d0 = ((uint32_t)v.x | ((uint32_t)v.y << 16)) * 0x3F80u;
            uint32_t d1 = ((uint32_t)v.z | ((uint32_t)v.w << 16)) * 0x3F80u;
            *reinterpret_cast<uint2*>(&Alds[(wave * 16 + n) * LDA + lane * 4]) = make_uint2(d0, d1);
        }
    }
    __syncthreads();   // the ONLY barrier; drains exactly the loads we need

    floatx4 acc[9];
    #pragma unroll
    for (int i = 0; i < 9; ++i) acc[i] = (floatx4)0.f;

    // B direct-from-global (L2-hot): row j*16+fm, 8 shorts at k = kbeg + w*32 + quad*8
    const unsigned short* bP = hT + (size_t)fm * NAG + kbeg + quad * 8;

    for (int w = 0; w < 8; ++w) {             // 8 K-windows of 32, barrier-free
        short8 af = *reinterpret_cast<const short8*>(&Alds[(wave * 16 + fm) * LDA + w * 32 + quad * 8]);
        #pragma unroll
        for (int j = 0; j < 9; ++j) {
            short8 bf = *reinterpret_cast<const short8*>(bP + (size_t)(j * 16) * NAG + w * 32);
            acc[j] = __builtin_amdgcn_mfma_f32_16x16x32_bf16(af, bf, acc[j], 0, 0, 0);
        }
    }

    // epilogue: C/D layout col=lane&15, row=quad*4+reg; fp16 private partial per K-split
    unsigned short* out = Cp16 + (size_t)ks * (NAG * NB);
    #pragma unroll
    for (int j = 0; j < 9; ++j) {
        int col = j * 16 + fm;
        #pragma unroll
        for (int r = 0; r < 4; ++r) {
            int row = row0 + wave * 16 + quad * 4 + r;
            out[(size_t)row * NB + col] = f2h(acc[j][r]);
        }
    }
}

// ---------------- Kernel 3: reduce fp16 partials, msg=sum/deg, actor MLP ----------------
__global__ __launch_bounds__(256) void k3_actor(
    const float* __restrict__ h_f32,          // [8192][128]
    const unsigned short* __restrict__ Cp16,  // [NSPLIT][8192][144] fp16
    const void* __restrict__ W2,              // [256][128]
    const void* __restrict__ b2,              // [128]
    const void* __restrict__ W3,              // [128][16]
    const void* __restrict__ b3,              // [16]
    const int* __restrict__ flag,
    void* __restrict__ out)                   // [8192][16]
{
    __shared__ float4 comb4[16][66];   // [agent][c-quad], c = 0..255
    __shared__ float hid[16][132];
    __shared__ float inv_lds[16];
    const int t = threadIdx.x;
    const int abase = blockIdx.x * 16;
    const bool isf = (*flag != 0);
    const size_t PS = (size_t)NAG * NB;

    if (t < 16) {
        float deg = 0.f;
        #pragma unroll
        for (int s = 0; s < NSPLIT; ++s)
            deg += h2f(Cp16[s * PS + (size_t)(abase + t) * NB + 128]);
        inv_lds[t] = 1.0f / fmaxf(deg, 1.0f);
    }
    __syncthreads();

    #pragma unroll
    for (int jj = 0; jj < 4; ++jj) {
        int idx = jj * 256 + t;
        int a = idx >> 6, q = idx & 63;
        float4 v;
        if (q < 32) {   // h part
            v = *reinterpret_cast<const float4*>(h_f32 + (size_t)(abase + a) * 128 + q * 4);
        } else {        // msg part: sum NSPLIT fp16 partials, scale by 1/deg
            int f = (q - 32) * 4;
            float s0 = 0.f, s1 = 0.f, s2 = 0.f, s3 = 0.f;
            #pragma unroll
            for (int s = 0; s < NSPLIT; ++s) {
                ushort4 p = *reinterpret_cast<const ushort4*>(Cp16 + s * PS + (size_t)(abase + a) * NB + f);
                s0 += h2f(p.x); s1 += h2f(p.y); s2 += h2f(p.z); s3 += h2f(p.w);
            }
            float sc = inv_lds[a];
            v = make_float4(s0 * sc, s1 * sc, s2 * sc, s3 * sc);
        }
        comb4[a][q] = v;
    }
    __syncthreads();

    const int o = t & 127, half = t >> 7;   // 8 agents per half
    float acc[8];
    if (isf) {
        const float* Wp = (const float*)W2;
        float bias = ((const float*)b2)[o];
        #pragma unroll
        for (int i = 0; i < 8; ++i) acc[i] = bias;
        for (int cq = 0; cq < 64; ++cq) {
            float w0 = Wp[(cq * 4 + 0) * 128 + o];
            float w1 = Wp[(cq * 4 + 1) * 128 + o];
            float w2 = Wp[(cq * 4 + 2) * 128 + o];
            float w3 = Wp[(cq * 4 + 3) * 128 + o];
            #pragma unroll
            for (int i = 0; i < 8; ++i) {
                float4 v = comb4[half * 8 + i][cq];
                acc[i] = fmaf(v.x, w0, acc[i]);
                acc[i] = fmaf(v.y, w1, acc[i]);
                acc[i] = fmaf(v.z, w2, acc[i]);
                acc[i] = fmaf(v.w, w3, acc[i]);
            }
        }
    } else {
        const unsigned short* Wp = (const unsigned short*)W2;
        float bias = bf2f(((const unsigned short*)b2)[o]);
        #pragma unroll
        for (int i = 0; i < 8; ++i) acc[i] = bias;
        for (int cq = 0; cq < 64; ++cq) {
            float w0 = bf2f(Wp[(cq * 4 + 0) * 128 + o]);
            float w1 = bf2f(Wp[(cq * 4 + 1) * 128 + o]);
            float w2 = bf2f(Wp[(cq * 4 + 2) * 128 + o]);
            float w3 = bf2f(Wp[(cq * 4 + 3) * 128 + o]);
            #pragma unroll
            for (int i = 0; i < 8; ++i) {
                float4 v = comb4[half * 8 + i][cq];
                acc[i] = fmaf(v.x, w0, acc[i]);
                acc[i] = fmaf(v.y, w1, acc[i]);
                acc[i] = fmaf(v.z, w2, acc[i]);
                acc[i] = fmaf(v.w, w3, acc[i]);
            }
        }
    }
    #pragma unroll
    for (int i = 0; i < 8; ++i)
        hid[half * 8 + i][o] = tanhf(acc[i]);
    __syncthreads();

    const int q = t & 15, ar = t >> 4;
    float l;
    if (isf) {
        const float* Wp = (const float*)W3;
        l = ((const float*)b3)[q];
        #pragma unroll 4
        for (int oo = 0; oo < 128; ++oo)
            l = fmaf(hid[ar][oo], Wp[oo * 16 + q], l);
    } else {
        const unsigned short* Wp = (const unsigned short*)W3;
        l = bf2f(((const unsigned short*)b3)[q]);
        #pragma unroll 4
        for (int oo = 0; oo < 128; ++oo)
            l = fmaf(hid[ar][oo], bf2f(Wp[oo * 16 + q]), l);
    }
    size_t i0 = (size_t)(abase + ar) * 16 + q;
    if (isf) ((float*)out)[i0] = l;
    else     ((unsigned short*)out)[i0] = f2bf(l);
}

extern "C" void kernel_launch(void* const* d_in, const int* in_sizes, int n_in,
                              void* d_out, int out_size, void* d_ws, size_t ws_size,
                              hipStream_t stream) {
    const void* obs = d_in[0];
    const int*  adj = (const int*)d_in[1];
    const void* W1  = d_in[2];
    const void* b1  = d_in[3];
    const void* W2  = d_in[4];
    const void* b2  = d_in[5];
    const void* W3  = d_in[6];
    const void* b3  = d_in[7];

    char* ws = (char*)d_ws;
    unsigned short* hT   = (unsigned short*)(ws);               // 144*8192*2    =  2,359,296 B
    float*          h_f32= (float*)(ws + 2359296);              // 8192*128*4    =  4,194,304 B
    unsigned short* Cp16 = (unsigned short*)(ws + 6553600);     // 32*8192*144*2 = 75,497,472 B
    int*            flag = (int*)(ws + 82051072);               // 4 B  (total ~82 MB)

    hipLaunchKernelGGL(k0_init, dim3(1), dim3(64), 0, stream, flag, (const unsigned short*)W1);
    hipLaunchKernelGGL(k1_encode, dim3(256), dim3(256), 0, stream, obs, W1, b1, flag, h_f32, hT);
    hipLaunchKernelGGL(k2_msggemm, dim3(4096), dim3(256), 0, stream, adj, hT, Cp16);
    hipLaunchKernelGGL(k3_actor, dim3(512), dim3(256), 0, stream, h_f32, Cp16, W2, b2, W3, b3, flag, d_out);
}

// Round 13
// 459.582 us; speedup vs baseline: 1.1166x; 1.1166x over previous
//
#include <hip/hip_runtime.h>
#include <stdint.h>
#include <math.h>

#define NAG 8192
#define NB  144          // partial row stride: 128 feats + deg col(128) + pad to 9*16
#define NSPLIT 8         // K splits of 1024 (fp16 private partials, no atomics)
#define LDB 264          // B LDS row stride in shorts (256 + 8 pad)

typedef __attribute__((ext_vector_type(8))) short short8;
typedef __attribute__((ext_vector_type(4))) float floatx4;

__device__ __forceinline__ float bf2f(unsigned short u) {
    union { uint32_t i; float f; } v; v.i = ((uint32_t)u) << 16; return v.f;
}
__device__ __forceinline__ unsigned short f2bf(float f) {
    union { float f; uint32_t i; } v; v.f = f;
    uint32_t x = v.i;
    return (unsigned short)((x + 0x7FFFu + ((x >> 16) & 1u)) >> 16);  // RNE
}
__device__ __forceinline__ unsigned short f2h(float f) {
    union { _Float16 h; unsigned short u; } v; v.h = (_Float16)f; return v.u;
}
__device__ __forceinline__ float h2f(unsigned short u) {
    union { _Float16 h; unsigned short u; } v; v.u = u; return (float)v.h;
}

// ---------------- Kernel 0: detect float storage dtype from W1 raw bits ----------------
__global__ __launch_bounds__(64) void k0_init(
    int* __restrict__ flag, const unsigned short* __restrict__ W1raw)
{
    int big = 0;
    #pragma unroll
    for (int j = 0; j < 8; ++j) {
        float v = bf2f(W1raw[threadIdx.x * 8 + j]);
        if (!(fabsf(v) <= 1e6f)) big = 1;   // catches huge and NaN (fp32 mantissa noise)
    }
    unsigned long long m = __ballot(big);
    if (threadIdx.x == 0) *flag = (m != 0ull) ? 1 : 0;
}

// ---------------- Kernel P: bitpack adj (268 MB int32 -> 8.4 MB bits) ----------------
// Pure streaming read, 256 B/wave-instr contiguous (the pattern the HW does at ~6.3 TB/s).
// bits[u] bit b  <->  adj_flat[u*64 + b] != 0   (natural LSB-first order).
__global__ __launch_bounds__(256) void kp_pack(
    const int* __restrict__ adj, unsigned long long* __restrict__ bits)
{
    const int lane = threadIdx.x & 63;
    const int gw = blockIdx.x * 4 + (threadIdx.x >> 6);   // global wave id 0..8191
    for (int it = 0; it < 32; ++it) {
        size_t u = ((size_t)it * 8192 + gw) * 4;          // 4 u64-units per wave per iter
        size_t col = u * 64 + lane;
        unsigned long long m0, m1, m2, m3;
        m0 = __ballot(adj[col]         != 0);
        m1 = __ballot(adj[col + 64]    != 0);
        m2 = __ballot(adj[col + 128]   != 0);
        m3 = __ballot(adj[col + 192]   != 0);
        if (lane == 0) {
            bits[u]     = m0;
            bits[u + 1] = m1;
            bits[u + 2] = m2;
            bits[u + 3] = m3;
        }
    }
}

// ---------------- Kernel 1: h = tanh(obs@W1+b1); write h_f32 and hT_bf16 ----------------
__global__ __launch_bounds__(256) void k1_encode(
    const void* __restrict__ obs,   // [8192][64] fp32 or bf16
    const void* __restrict__ W1,    // [64][128]
    const void* __restrict__ b1,    // [128]
    const int* __restrict__ flag,
    float* __restrict__ h_f32,      // [8192][128]
    unsigned short* __restrict__ hT)// [144][8192] bf16 (row128=ones, 129..143=0)
{
    __shared__ float obs_lds[32][68];
    __shared__ unsigned short ht_lds[128][33];
    const int t = threadIdx.x;
    const int abase = blockIdx.x * 32;
    const bool isf = (*flag != 0);

    {   // stage obs tile 32x64
        int a = t >> 3, c0 = (t & 7) * 8;
        if (isf) {
            const float* p = (const float*)obs;
            #pragma unroll
            for (int j = 0; j < 8; ++j)
                obs_lds[a][c0 + j] = p[(size_t)(abase + a) * 64 + c0 + j];
        } else {
            const unsigned short* p = (const unsigned short*)obs;
            #pragma unroll
            for (int j = 0; j < 8; ++j)
                obs_lds[a][c0 + j] = bf2f(p[(size_t)(abase + a) * 64 + c0 + j]);
        }
    }
    __syncthreads();

    const int o = t & 127;
    const int half = t >> 7;          // wave-uniform
    float acc[16];
    if (isf) {
        const float* Wp = (const float*)W1;
        float bias = ((const float*)b1)[o];
        #pragma unroll
        for (int i = 0; i < 16; ++i) acc[i] = bias;
        for (int k0 = 0; k0 < 64; k0 += 8) {
            float w[8];
            #pragma unroll
            for (int j = 0; j < 8; ++j) w[j] = Wp[(k0 + j) * 128 + o];
            #pragma unroll
            for (int j = 0; j < 8; ++j)
                #pragma unroll
                for (int i = 0; i < 16; ++i)
                    acc[i] = fmaf(obs_lds[half * 16 + i][k0 + j], w[j], acc[i]);
        }
    } else {
        const unsigned short* Wp = (const unsigned short*)W1;
        float bias = bf2f(((const unsigned short*)b1)[o]);
        #pragma unroll
        for (int i = 0; i < 16; ++i) acc[i] = bias;
        for (int k0 = 0; k0 < 64; k0 += 8) {
            float w[8];
            #pragma unroll
            for (int j = 0; j < 8; ++j) w[j] = bf2f(Wp[(k0 + j) * 128 + o]);
            #pragma unroll
            for (int j = 0; j < 8; ++j)
                #pragma unroll
                for (int i = 0; i < 16; ++i)
                    acc[i] = fmaf(obs_lds[half * 16 + i][k0 + j], w[j], acc[i]);
        }
    }
    #pragma unroll
    for (int i = 0; i < 16; ++i) {
        float th = tanhf(acc[i]);
        int a = half * 16 + i;
        h_f32[(size_t)(abase + a) * 128 + o] = th;
        ht_lds[o][a] = f2bf(th);
    }
    __syncthreads();

    for (int p = 0; p < 18; ++p) {
        int n = p * 8 + (t >> 5);
        int a = t & 31;
        unsigned short v;
        if (n < 128)       v = ht_lds[n][a];
        else if (n == 128) v = 0x3F80;     // 1.0 bf16 -> deg column
        else               v = 0;
        hT[(size_t)n * NAG + abase + a] = v;
    }
}

// ---------------- Kernel 2: Cp16[ks] = bits-adj @ [h|1|0]  (bf16 MFMA) ----------------
// A from the 8.4 MB bit-matrix: each lane's 256-k A-slice = 8 u32 IN REGISTERS (32 B load);
// expand byte->bf16 {0,1} at MFMA time (~5 VALU/pair, amortized over 9 N-tiles). B K-slice
// staged in LDS (76 KB -> 2 blocks/CU) per 256-k sub-slice; barriers only wait on loads
// that are needed. Nothing but acc lives across barriers (spill-proof class: r2/r11).
__global__ __launch_bounds__(256, 2) void k2_msggemm(
    const uint32_t* __restrict__ bits,        // [8192][256] u32, bit b of word w = col w*32+b
    const unsigned short* __restrict__ hT,    // [144][8192] bf16
    unsigned short* __restrict__ Cp16)        // [NSPLIT][8192][144] fp16
{
    __shared__ __align__(16) unsigned short Blds[144 * LDB];  // 76,032 B
    const int t = threadIdx.x;
    const int mtile = blockIdx.x & 127;       // 128 M-tiles of 64 rows
    const int ks = blockIdx.x >> 7;           // 8 K-splits of 1024
    const int row0 = mtile * 64;
    const int kbeg = ks * 1024;

    const int wave = t >> 6, lane = t & 63;
    const int fm = lane & 15, quad = lane >> 4;

    floatx4 acc[9];
    #pragma unroll
    for (int i = 0; i < 9; ++i) acc[i] = (floatx4)0.f;

    const int arow = row0 + wave * 16 + fm;
    const uint32_t* aWp = bits + (size_t)arow * 256 + (kbeg >> 5);

    for (int ss = 0; ss < 4; ++ss) {          // 4 sub-slices of 256 k
        if (ss) __syncthreads();              // prior compute done before LDS overwrite
        // stage B[144][256] (L2-hot hT)
        #pragma unroll 9
        for (int i = 0; i < 18; ++i) {
            int idx = i * 256 + t;
            int row = idx >> 5, ch = idx & 31;
            uint4 v = *reinterpret_cast<const uint4*>(hT + (size_t)row * NAG + kbeg + ss * 256 + ch * 8);
            *reinterpret_cast<uint4*>(&Blds[row * LDB + ch * 8]) = v;
        }
        // lane A-bits for this sub-slice: 8 u32 = 32 B
        int4 a0 = *reinterpret_cast<const int4*>(aWp + ss * 8);
        int4 a1 = *reinterpret_cast<const int4*>(aWp + ss * 8 + 4);
        uint32_t aw[8] = {(uint32_t)a0.x, (uint32_t)a0.y, (uint32_t)a0.z, (uint32_t)a0.w,
                          (uint32_t)a1.x, (uint32_t)a1.y, (uint32_t)a1.z, (uint32_t)a1.w};
        __syncthreads();                      // B + bits resident
        #pragma unroll
        for (int kw = 0; kw < 8; ++kw) {      // 8 windows of 32 k
            uint32_t b = (aw[kw] >> (quad * 8)) & 0xFFu;
            union { uint32_t u[4]; short8 s; } af;
            #pragma unroll
            for (int p = 0; p < 4; ++p) {
                uint32_t bb = b >> (2 * p);
                af.u[p] = ((bb & 1u) | ((bb & 2u) << 15)) * 0x3F80u;   // {0,1}->bf16 pair, exact
            }
            #pragma unroll
            for (int j = 0; j < 9; ++j) {
                short8 bf = *reinterpret_cast<const short8*>(&Blds[(j * 16 + fm) * LDB + kw * 32 + quad * 8]);
                acc[j] = __builtin_amdgcn_mfma_f32_16x16x32_bf16(af.s, bf, acc[j], 0, 0, 0);
            }
        }
    }

    // epilogue: C/D layout col=lane&15, row=quad*4+reg; fp16 private partial per K-split
    unsigned short* out = Cp16 + (size_t)ks * (NAG * NB);
    #pragma unroll
    for (int j = 0; j < 9; ++j) {
        int col = j * 16 + fm;
        #pragma unroll
        for (int r = 0; r < 4; ++r) {
            int row = row0 + wave * 16 + quad * 4 + r;
            out[(size_t)row * NB + col] = f2h(acc[j][r]);
        }
    }
}

// ---------------- Kernel 3: reduce fp16 partials, msg=sum/deg, actor MLP ----------------
__global__ __launch_bounds__(256) void k3_actor(
    const float* __restrict__ h_f32,          // [8192][128]
    const unsigned short* __restrict__ Cp16,  // [NSPLIT][8192][144] fp16
    const void* __restrict__ W2,              // [256][128]
    const void* __restrict__ b2,              // [128]
    const void* __restrict__ W3,              // [128][16]
    const void* __restrict__ b3,              // [16]
    const int* __restrict__ flag,
    void* __restrict__ out)                   // [8192][16]
{
    __shared__ float4 comb4[16][66];   // [agent][c-quad], c = 0..255
    __shared__ float hid[16][132];
    __shared__ float inv_lds[16];
    const int t = threadIdx.x;
    const int abase = blockIdx.x * 16;
    const bool isf = (*flag != 0);
    const size_t PS = (size_t)NAG * NB;

    if (t < 16) {
        float deg = 0.f;
        #pragma unroll
        for (int s = 0; s < NSPLIT; ++s)
            deg += h2f(Cp16[s * PS + (size_t)(abase + t) * NB + 128]);
        inv_lds[t] = 1.0f / fmaxf(deg, 1.0f);
    }
    __syncthreads();

    #pragma unroll
    for (int jj = 0; jj < 4; ++jj) {
        int idx = jj * 256 + t;
        int a = idx >> 6, q = idx & 63;
        float4 v;
        if (q < 32) {   // h part
            v = *reinterpret_cast<const float4*>(h_f32 + (size_t)(abase + a) * 128 + q * 4);
        } else {        // msg part: sum NSPLIT fp16 partials, scale by 1/deg
            int f = (q - 32) * 4;
            float s0 = 0.f, s1 = 0.f, s2 = 0.f, s3 = 0.f;
            #pragma unroll
            for (int s = 0; s < NSPLIT; ++s) {
                ushort4 p = *reinterpret_cast<const ushort4*>(Cp16 + s * PS + (size_t)(abase + a) * NB + f);
                s0 += h2f(p.x); s1 += h2f(p.y); s2 += h2f(p.z); s3 += h2f(p.w);
            }
            float sc = inv_lds[a];
            v = make_float4(s0 * sc, s1 * sc, s2 * sc, s3 * sc);
        }
        comb4[a][q] = v;
    }
    __syncthreads();

    const int o = t & 127, half = t >> 7;   // 8 agents per half
    float acc[8];
    if (isf) {
        const float* Wp = (const float*)W2;
        float bias = ((const float*)b2)[o];
        #pragma unroll
        for (int i = 0; i < 8; ++i) acc[i] = bias;
        for (int cq = 0; cq < 64; ++cq) {
            float w0 = Wp[(cq * 4 + 0) * 128 + o];
            float w1 = Wp[(cq * 4 + 1) * 128 + o];
            float w2 = Wp[(cq * 4 + 2) * 128 + o];
            float w3 = Wp[(cq * 4 + 3) * 128 + o];
            #pragma unroll
            for (int i = 0; i < 8; ++i) {
                float4 v = comb4[half * 8 + i][cq];
                acc[i] = fmaf(v.x, w0, acc[i]);
                acc[i] = fmaf(v.y, w1, acc[i]);
                acc[i] = fmaf(v.z, w2, acc[i]);
                acc[i] = fmaf(v.w, w3, acc[i]);
            }
        }
    } else {
        const unsigned short* Wp = (const unsigned short*)W2;
        float bias = bf2f(((const unsigned short*)b2)[o]);
        #pragma unroll
        for (int i = 0; i < 8; ++i) acc[i] = bias;
        for (int cq = 0; cq < 64; ++cq) {
            float w0 = bf2f(Wp[(cq * 4 + 0) * 128 + o]);
            float w1 = bf2f(Wp[(cq * 4 + 1) * 128 + o]);
            float w2 = bf2f(Wp[(cq * 4 + 2) * 128 + o]);
            float w3 = bf2f(Wp[(cq * 4 + 3) * 128 + o]);
            #pragma unroll
            for (int i = 0; i < 8; ++i) {
                float4 v = comb4[half * 8 + i][cq];
                acc[i] = fmaf(v.x, w0, acc[i]);
                acc[i] = fmaf(v.y, w1, acc[i]);
                acc[i] = fmaf(v.z, w2, acc[i]);
                acc[i] = fmaf(v.w, w3, acc[i]);
            }
        }
    }
    #pragma unroll
    for (int i = 0; i < 8; ++i)
        hid[half * 8 + i][o] = tanhf(acc[i]);
    __syncthreads();

    const int q = t & 15, ar = t >> 4;
    float l;
    if (isf) {
        const float* Wp = (const float*)W3;
        l = ((const float*)b3)[q];
        #pragma unroll 4
        for (int oo = 0; oo < 128; ++oo)
            l = fmaf(hid[ar][oo], Wp[oo * 16 + q], l);
    } else {
        const unsigned short* Wp = (const unsigned short*)W3;
        l = bf2f(((const unsigned short*)b3)[q]);
        #pragma unroll 4
        for (int oo = 0; oo < 128; ++oo)
            l = fmaf(hid[ar][oo], bf2f(Wp[oo * 16 + q]), l);
    }
    size_t i0 = (size_t)(abase + ar) * 16 + q;
    if (isf) ((float*)out)[i0] = l;
    else     ((unsigned short*)out)[i0] = f2bf(l);
}

extern "C" void kernel_launch(void* const* d_in, const int* in_sizes, int n_in,
                              void* d_out, int out_size, void* d_ws, size_t ws_size,
                              hipStream_t stream) {
    const void* obs = d_in[0];
    const int*  adj = (const int*)d_in[1];
    const void* W1  = d_in[2];
    const void* b1  = d_in[3];
    const void* W2  = d_in[4];
    const void* b2  = d_in[5];
    const void* W3  = d_in[6];
    const void* b3  = d_in[7];

    char* ws = (char*)d_ws;
    unsigned short* hT   = (unsigned short*)(ws);                  // 144*8192*2   =  2,359,296 B
    float*          h_f32= (float*)(ws + 2359296);                 // 8192*128*4   =  4,194,304 B
    unsigned short* Cp16 = (unsigned short*)(ws + 6553600);        // 8*8192*144*2 = 18,874,368 B
    unsigned long long* bits = (unsigned long long*)(ws + 25427968); // 8192*8192/8 = 8,388,608 B
    int*            flag = (int*)(ws + 33816576);                  // 4 B  (total ~33.8 MB)

    hipLaunchKernelGGL(k0_init, dim3(1), dim3(64), 0, stream, flag, (const unsigned short*)W1);
    hipLaunchKernelGGL(kp_pack, dim3(2048), dim3(256), 0, stream, adj, bits);
    hipLaunchKernelGGL(k1_encode, dim3(256), dim3(256), 0, stream, obs, W1, b1, flag, h_f32, hT);
    hipLaunchKernelGGL(k2_msggemm, dim3(1024), dim3(256), 0, stream,
                       (const uint32_t*)bits, hT, Cp16);
    hipLaunchKernelGGL(k3_actor, dim3(512), dim3(256), 0, stream, h_f32, Cp16, W2, b2, W3, b3, flag, d_out);
}

// Round 14
// 434.901 us; speedup vs baseline: 1.1799x; 1.0568x over previous
//
#include <hip/hip_runtime.h>
#include <stdint.h>
#include <math.h>

#define NAG 8192
#define NB  144          // partial row stride: 128 feats + deg col(128) + pad to 9*16
#define NSPLIT 8         // K splits of 1024 (fp16 private partials, no atomics)
#define LDB2 136         // B LDS row stride in shorts (128 + 8 pad)

typedef __attribute__((ext_vector_type(8))) short short8;
typedef __attribute__((ext_vector_type(4))) float floatx4;

__device__ __forceinline__ float bf2f(unsigned short u) {
    union { uint32_t i; float f; } v; v.i = ((uint32_t)u) << 16; return v.f;
}
__device__ __forceinline__ unsigned short f2bf(float f) {
    union { float f; uint32_t i; } v; v.f = f;
    uint32_t x = v.i;
    return (unsigned short)((x + 0x7FFFu + ((x >> 16) & 1u)) >> 16);  // RNE
}
__device__ __forceinline__ unsigned short f2h(float f) {
    union { _Float16 h; unsigned short u; } v; v.h = (_Float16)f; return v.u;
}
__device__ __forceinline__ float h2f(unsigned short u) {
    union { _Float16 h; unsigned short u; } v; v.u = u; return (float)v.h;
}
// per-wave dtype self-detection: every wave scans W1[0..511] -> identical ballot in
// every wave -> uniform isf without any cross-block flag dependency (k0 eliminated)
__device__ __forceinline__ bool detect_f32(const void* W1, int t) {
    const unsigned short* w = (const unsigned short*)W1;
    int l = t & 63, big = 0;
    #pragma unroll
    for (int j = 0; j < 8; ++j) {
        float v = bf2f(w[l * 8 + j]);
        if (!(fabsf(v) <= 1e6f)) big = 1;   // catches huge and NaN (fp32 mantissa noise)
    }
    return __ballot(big) != 0ull;
}

// ---------------- Kernel A: fused bitpack (blocks 0..2047) + encoder (2048..2303) ----------------
__global__ __launch_bounds__(256) void kA_pack_encode(
    const int* __restrict__ adj,              // [8192][8192] int32 {0,1}
    unsigned long long* __restrict__ bits,    // [8192*8192/64] packed
    const void* __restrict__ obs,             // [8192][64]
    const void* __restrict__ W1,              // [64][128]
    const void* __restrict__ b1,              // [128]
    float* __restrict__ h_f32,                // [8192][128]
    unsigned short* __restrict__ hT)          // [144][8192] bf16
{
    const int t = threadIdx.x;
    if (blockIdx.x < 2048) {
        // ---- bitpack: pure streaming, 4KB contiguous per wave-iter ----
        const int lane = t & 63;
        const int gw = blockIdx.x * 4 + (t >> 6);         // global wave id 0..8191
        for (int it = 0; it < 32; ++it) {
            size_t u = ((size_t)it * 8192 + gw) * 4;      // 4 u64-units per wave per iter
            size_t col = u * 64 + lane;
            unsigned long long m0 = __ballot(adj[col]       != 0);
            unsigned long long m1 = __ballot(adj[col + 64]  != 0);
            unsigned long long m2 = __ballot(adj[col + 128] != 0);
            unsigned long long m3 = __ballot(adj[col + 192] != 0);
            if (lane == 0) {
                bits[u]     = m0;
                bits[u + 1] = m1;
                bits[u + 2] = m2;
                bits[u + 3] = m3;
            }
        }
        return;
    }
    // ---- encoder: h = tanh(obs@W1+b1) ----
    __shared__ float obs_lds[32][68];
    __shared__ unsigned short ht_lds[128][33];
    const int abase = (blockIdx.x - 2048) * 32;
    const bool isf = detect_f32(W1, t);

    {   // stage obs tile 32x64
        int a = t >> 3, c0 = (t & 7) * 8;
        if (isf) {
            const float* p = (const float*)obs;
            #pragma unroll
            for (int j = 0; j < 8; ++j)
                obs_lds[a][c0 + j] = p[(size_t)(abase + a) * 64 + c0 + j];
        } else {
            const unsigned short* p = (const unsigned short*)obs;
            #pragma unroll
            for (int j = 0; j < 8; ++j)
                obs_lds[a][c0 + j] = bf2f(p[(size_t)(abase + a) * 64 + c0 + j]);
        }
    }
    __syncthreads();

    const int o = t & 127;
    const int half = t >> 7;          // wave-uniform
    float acc[16];
    if (isf) {
        const float* Wp = (const float*)W1;
        float bias = ((const float*)b1)[o];
        #pragma unroll
        for (int i = 0; i < 16; ++i) acc[i] = bias;
        for (int k0 = 0; k0 < 64; k0 += 8) {
            float w[8];
            #pragma unroll
            for (int j = 0; j < 8; ++j) w[j] = Wp[(k0 + j) * 128 + o];
            #pragma unroll
            for (int j = 0; j < 8; ++j)
                #pragma unroll
                for (int i = 0; i < 16; ++i)
                    acc[i] = fmaf(obs_lds[half * 16 + i][k0 + j], w[j], acc[i]);
        }
    } else {
        const unsigned short* Wp = (const unsigned short*)W1;
        float bias = bf2f(((const unsigned short*)b1)[o]);
        #pragma unroll
        for (int i = 0; i < 16; ++i) acc[i] = bias;
        for (int k0 = 0; k0 < 64; k0 += 8) {
            float w[8];
            #pragma unroll
            for (int j = 0; j < 8; ++j) w[j] = bf2f(Wp[(k0 + j) * 128 + o]);
            #pragma unroll
            for (int j = 0; j < 8; ++j)
                #pragma unroll
                for (int i = 0; i < 16; ++i)
                    acc[i] = fmaf(obs_lds[half * 16 + i][k0 + j], w[j], acc[i]);
        }
    }
    #pragma unroll
    for (int i = 0; i < 16; ++i) {
        float th = tanhf(acc[i]);
        int a = half * 16 + i;
        h_f32[(size_t)(abase + a) * 128 + o] = th;
        ht_lds[o][a] = f2bf(th);
    }
    __syncthreads();

    for (int p = 0; p < 18; ++p) {
        int n = p * 8 + (t >> 5);
        int a = t & 31;
        unsigned short v;
        if (n < 128)       v = ht_lds[n][a];
        else if (n == 128) v = 0x3F80;     // 1.0 bf16 -> deg column
        else               v = 0;
        hT[(size_t)n * NAG + abase + a] = v;
    }
}

// ---------------- Kernel 2: Cp16[ks] = bits-adj @ [h|1|0]  (bf16 MFMA) ----------------
// A from the 8.4 MB bit-matrix (r13, proven); sub-slice BK=128 -> LDS 39.2 KB -> 4 blocks/CU
// (r13 was 76KB/2 blocks -> 8 waves/CU; doubling occupancy hides the staging barriers).
__global__ __launch_bounds__(256, 4) void k2_msggemm(
    const uint32_t* __restrict__ bits,        // [8192][256] u32, bit b of word w = col w*32+b
    const unsigned short* __restrict__ hT,    // [144][8192] bf16
    unsigned short* __restrict__ Cp16)        // [NSPLIT][8192][144] fp16
{
    __shared__ __align__(16) unsigned short Blds[144 * LDB2];  // 39,168 B
    const int t = threadIdx.x;
    const int mtile = blockIdx.x & 127;       // 128 M-tiles of 64 rows
    const int ks = blockIdx.x >> 7;           // 8 K-splits of 1024
    const int row0 = mtile * 64;
    const int kbeg = ks * 1024;

    const int wave = t >> 6, lane = t & 63;
    const int fm = lane & 15, quad = lane >> 4;

    floatx4 acc[9];
    #pragma unroll
    for (int i = 0; i < 9; ++i) acc[i] = (floatx4)0.f;

    const int arow = row0 + wave * 16 + fm;
    const uint32_t* aWp = bits + (size_t)arow * 256 + (kbeg >> 5);

    for (int ss = 0; ss < 8; ++ss) {          // 8 sub-slices of 128 k
        if (ss) __syncthreads();              // prior compute done before LDS overwrite
        // stage B[144][128] (L2-hot hT): 2304 16B-chunks over 256 threads = 9 each
        #pragma unroll
        for (int i = 0; i < 9; ++i) {
            int idx = i * 256 + t;
            int row = idx >> 4, ch = idx & 15;
            uint4 v = *reinterpret_cast<const uint4*>(hT + (size_t)row * NAG + kbeg + ss * 128 + ch * 8);
            *reinterpret_cast<uint4*>(&Blds[row * LDB2 + ch * 8]) = v;
        }
        // lane A-bits for this sub-slice: 4 u32 = 16 B
        int4 a0 = *reinterpret_cast<const int4*>(aWp + ss * 4);
        uint32_t aw[4] = {(uint32_t)a0.x, (uint32_t)a0.y, (uint32_t)a0.z, (uint32_t)a0.w};
        __syncthreads();                      // B + bits resident
        #pragma unroll
        for (int kw = 0; kw < 4; ++kw) {      // 4 windows of 32 k
            uint32_t b = (aw[kw] >> (quad * 8)) & 0xFFu;
            union { uint32_t u[4]; short8 s; } af;
            #pragma unroll
            for (int p = 0; p < 4; ++p) {
                uint32_t bb = b >> (2 * p);
                af.u[p] = ((bb & 1u) | ((bb & 2u) << 15)) * 0x3F80u;   // {0,1}->bf16 pair, exact
            }
            #pragma unroll
            for (int j = 0; j < 9; ++j) {
                short8 bf = *reinterpret_cast<const short8*>(&Blds[(j * 16 + fm) * LDB2 + kw * 32 + quad * 8]);
                acc[j] = __builtin_amdgcn_mfma_f32_16x16x32_bf16(af.s, bf, acc[j], 0, 0, 0);
            }
        }
    }

    // epilogue: C/D layout col=lane&15, row=quad*4+reg; fp16 private partial per K-split
    unsigned short* out = Cp16 + (size_t)ks * (NAG * NB);
    #pragma unroll
    for (int j = 0; j < 9; ++j) {
        int col = j * 16 + fm;
        #pragma unroll
        for (int r = 0; r < 4; ++r) {
            int row = row0 + wave * 16 + quad * 4 + r;
            out[(size_t)row * NB + col] = f2h(acc[j][r]);
        }
    }
}

// ---------------- Kernel 3: reduce fp16 partials, msg=sum/deg, actor MLP ----------------
// 8 agents/block -> 1024 blocks (4/CU): 2x parallelism vs r13.
__global__ __launch_bounds__(256) void k3_actor(
    const float* __restrict__ h_f32,          // [8192][128]
    const unsigned short* __restrict__ Cp16,  // [NSPLIT][8192][144] fp16
    const void* __restrict__ W1,              // for dtype self-detection
    const void* __restrict__ W2,              // [256][128]
    const void* __restrict__ b2,              // [128]
    const void* __restrict__ W3,              // [128][16]
    const void* __restrict__ b3,              // [16]
    void* __restrict__ out)                   // [8192][16]
{
    __shared__ float4 comb4[8][66];   // [agent][c-quad], c = 0..255
    __shared__ float hid[8][132];
    __shared__ float inv_lds[8];
    const int t = threadIdx.x;
    const int abase = blockIdx.x * 8;
    const bool isf = detect_f32(W1, t);
    const size_t PS = (size_t)NAG * NB;

    if (t < 8) {
        float deg = 0.f;
        #pragma unroll
        for (int s = 0; s < NSPLIT; ++s)
            deg += h2f(Cp16[s * PS + (size_t)(abase + t) * NB + 128]);
        inv_lds[t] = 1.0f / fmaxf(deg, 1.0f);
    }
    __syncthreads();

    // stage comb: 8 agents x 64 c-quads = 512 tasks over 256 threads
    #pragma unroll
    for (int jj = 0; jj < 2; ++jj) {
        int idx = jj * 256 + t;
        int a = idx >> 6, q = idx & 63;
        float4 v;
        if (q < 32) {   // h part
            v = *reinterpret_cast<const float4*>(h_f32 + (size_t)(abase + a) * 128 + q * 4);
        } else {        // msg part: sum NSPLIT fp16 partials, scale by 1/deg
            int f = (q - 32) * 4;
            float s0 = 0.f, s1 = 0.f, s2 = 0.f, s3 = 0.f;
            #pragma unroll
            for (int s = 0; s < NSPLIT; ++s) {
                ushort4 p = *reinterpret_cast<const ushort4*>(Cp16 + s * PS + (size_t)(abase + a) * NB + f);
                s0 += h2f(p.x); s1 += h2f(p.y); s2 += h2f(p.z); s3 += h2f(p.w);
            }
            float sc = inv_lds[a];
            v = make_float4(s0 * sc, s1 * sc, s2 * sc, s3 * sc);
        }
        comb4[a][q] = v;
    }
    __syncthreads();

    const int o = t & 127, half = t >> 7;   // 4 agents per half
    float acc[4];
    if (isf) {
        const float* Wp = (const float*)W2;
        float bias = ((const float*)b2)[o];
        #pragma unroll
        for (int i = 0; i < 4; ++i) acc[i] = bias;
        for (int cq = 0; cq < 64; ++cq) {
            float w0 = Wp[(cq * 4 + 0) * 128 + o];
            float w1 = Wp[(cq * 4 + 1) * 128 + o];
            float w2 = Wp[(cq * 4 + 2) * 128 + o];
            float w3 = Wp[(cq * 4 + 3) * 128 + o];
            #pragma unroll
            for (int i = 0; i < 4; ++i) {
                float4 v = comb4[half * 4 + i][cq];
                acc[i] = fmaf(v.x, w0, acc[i]);
                acc[i] = fmaf(v.y, w1, acc[i]);
                acc[i] = fmaf(v.z, w2, acc[i]);
                acc[i] = fmaf(v.w, w3, acc[i]);
            }
        }
    } else {
        const unsigned short* Wp = (const unsigned short*)W2;
        float bias = bf2f(((const unsigned short*)b2)[o]);
        #pragma unroll
        for (int i = 0; i < 4; ++i) acc[i] = bias;
        for (int cq = 0; cq < 64; ++cq) {
            float w0 = bf2f(Wp[(cq * 4 + 0) * 128 + o]);
            float w1 = bf2f(Wp[(cq * 4 + 1) * 128 + o]);
            float w2 = bf2f(Wp[(cq * 4 + 2) * 128 + o]);
            float w3 = bf2f(Wp[(cq * 4 + 3) * 128 + o]);
            #pragma unroll
            for (int i = 0; i < 4; ++i) {
                float4 v = comb4[half * 4 + i][cq];
                acc[i] = fmaf(v.x, w0, acc[i]);
                acc[i] = fmaf(v.y, w1, acc[i]);
                acc[i] = fmaf(v.z, w2, acc[i]);
                acc[i] = fmaf(v.w, w3, acc[i]);
            }
        }
    }
    #pragma unroll
    for (int i = 0; i < 4; ++i)
        hid[half * 4 + i][o] = tanhf(acc[i]);
    __syncthreads();

    if (t < 128) {   // 8 agents x 16 outputs
        const int q = t & 15, ar = t >> 4;
        float l;
        if (isf) {
            const float* Wp = (const float*)W3;
            l = ((const float*)b3)[q];
            #pragma unroll 4
            for (int oo = 0; oo < 128; ++oo)
                l = fmaf(hid[ar][oo], Wp[oo * 16 + q], l);
        } else {
            const unsigned short* Wp = (const unsigned short*)W3;
            l = bf2f(((const unsigned short*)b3)[q]);
            #pragma unroll 4
            for (int oo = 0; oo < 128; ++oo)
                l = fmaf(hid[ar][oo], bf2f(Wp[oo * 16 + q]), l);
        }
        size_t i0 = (size_t)(abase + ar) * 16 + q;
        if (isf) ((float*)out)[i0] = l;
        else     ((unsigned short*)out)[i0] = f2bf(l);
    }
}

extern "C" void kernel_launch(void* const* d_in, const int* in_sizes, int n_in,
                              void* d_out, int out_size, void* d_ws, size_t ws_size,
                              hipStream_t stream) {
    const void* obs = d_in[0];
    const int*  adj = (const int*)d_in[1];
    const void* W1  = d_in[2];
    const void* b1  = d_in[3];
    const void* W2  = d_in[4];
    const void* b2  = d_in[5];
    const void* W3  = d_in[6];
    const void* b3  = d_in[7];

    char* ws = (char*)d_ws;
    unsigned short* hT   = (unsigned short*)(ws);                  // 144*8192*2   =  2,359,296 B
    float*          h_f32= (float*)(ws + 2359296);                 // 8192*128*4   =  4,194,304 B
    unsigned short* Cp16 = (unsigned short*)(ws + 6553600);        // 8*8192*144*2 = 18,874,368 B
    unsigned long long* bits = (unsigned long long*)(ws + 25427968); // 8192*8192/8 = 8,388,608 B
                                                                   // total ~33.8 MB

    hipLaunchKernelGGL(kA_pack_encode, dim3(2304), dim3(256), 0, stream,
                       adj, bits, obs, W1, b1, h_f32, hT);
    hipLaunchKernelGGL(k2_msggemm, dim3(1024), dim3(256), 0, stream,
                       (const uint32_t*)bits, hT, Cp16);
    hipLaunchKernelGGL(k3_actor, dim3(1024), dim3(256), 0, stream,
                       h_f32, Cp16, W1, W2, b2, W3, b3, d_out);
}

// Round 15
// 430.884 us; speedup vs baseline: 1.1909x; 1.0093x over previous
//
#include <hip/hip_runtime.h>
#include <stdint.h>
#include <math.h>

#define NAG 8192
#define NC  128          // Cp16 row stride: exactly the 128 msg features
#define NSPLIT 8         // K splits of 1024 (fp16 private partials, no atomics)
#define LDB2 136         // B LDS row stride in shorts (128 + 8 pad)

typedef __attribute__((ext_vector_type(8))) short short8;
typedef __attribute__((ext_vector_type(4))) float floatx4;

__device__ __forceinline__ float bf2f(unsigned short u) {
    union { uint32_t i; float f; } v; v.i = ((uint32_t)u) << 16; return v.f;
}
__device__ __forceinline__ unsigned short f2bf(float f) {
    union { float f; uint32_t i; } v; v.f = f;
    uint32_t x = v.i;
    return (unsigned short)((x + 0x7FFFu + ((x >> 16) & 1u)) >> 16);  // RNE
}
__device__ __forceinline__ unsigned short f2h(float f) {
    union { _Float16 h; unsigned short u; } v; v.h = (_Float16)f; return v.u;
}
__device__ __forceinline__ float h2f(unsigned short u) {
    union { _Float16 h; unsigned short u; } v; v.u = u; return (float)v.h;
}
// per-wave dtype self-detection (uniform ballot in every wave; no cross-block flag)
__device__ __forceinline__ bool detect_f32(const void* W1, int t) {
    const unsigned short* w = (const unsigned short*)W1;
    int l = t & 63, big = 0;
    #pragma unroll
    for (int j = 0; j < 8; ++j) {
        float v = bf2f(w[l * 8 + j]);
        if (!(fabsf(v) <= 1e6f)) big = 1;   // catches huge and NaN (fp32 mantissa noise)
    }
    return __ballot(big) != 0ull;
}

// ---------------- Kernel A: fused bitpack (blocks 0..2047) + encoder (2048..2303) ----------------
__global__ __launch_bounds__(256) void kA_pack_encode(
    const int* __restrict__ adj,              // [8192][8192] int32 {0,1}
    unsigned long long* __restrict__ bits,    // [8192*8192/64] packed, row-major
    const void* __restrict__ obs,             // [8192][64]
    const void* __restrict__ W1,              // [64][128]
    const void* __restrict__ b1,              // [128]
    float* __restrict__ h_f32,                // [8192][128]
    unsigned short* __restrict__ hT)          // [128][8192] bf16 (features only)
{
    const int t = threadIdx.x;
    if (blockIdx.x < 2048) {
        // ---- bitpack: pure streaming, 1KB contiguous per ballot, 4KB per wave-iter ----
        const int lane = t & 63;
        const int gw = blockIdx.x * 4 + (t >> 6);         // global wave id 0..8191
        for (int it = 0; it < 32; ++it) {
            size_t u = ((size_t)it * 8192 + gw) * 4;      // 4 u64-units per wave per iter
            size_t col = u * 64 + lane;
            unsigned long long m0 = __ballot(adj[col]       != 0);
            unsigned long long m1 = __ballot(adj[col + 64]  != 0);
            unsigned long long m2 = __ballot(adj[col + 128] != 0);
            unsigned long long m3 = __ballot(adj[col + 192] != 0);
            if (lane == 0) {
                bits[u]     = m0;
                bits[u + 1] = m1;
                bits[u + 2] = m2;
                bits[u + 3] = m3;
            }
        }
        return;
    }
    // ---- encoder: h = tanh(obs@W1+b1) ----
    __shared__ float obs_lds[32][68];
    __shared__ unsigned short ht_lds[128][33];
    const int abase = (blockIdx.x - 2048) * 32;
    const bool isf = detect_f32(W1, t);

    {   // stage obs tile 32x64
        int a = t >> 3, c0 = (t & 7) * 8;
        if (isf) {
            const float* p = (const float*)obs;
            #pragma unroll
            for (int j = 0; j < 8; ++j)
                obs_lds[a][c0 + j] = p[(size_t)(abase + a) * 64 + c0 + j];
        } else {
            const unsigned short* p = (const unsigned short*)obs;
            #pragma unroll
            for (int j = 0; j < 8; ++j)
                obs_lds[a][c0 + j] = bf2f(p[(size_t)(abase + a) * 64 + c0 + j]);
        }
    }
    __syncthreads();

    const int o = t & 127;
    const int half = t >> 7;          // wave-uniform
    float acc[16];
    if (isf) {
        const float* Wp = (const float*)W1;
        float bias = ((const float*)b1)[o];
        #pragma unroll
        for (int i = 0; i < 16; ++i) acc[i] = bias;
        for (int k0 = 0; k0 < 64; k0 += 8) {
            float w[8];
            #pragma unroll
            for (int j = 0; j < 8; ++j) w[j] = Wp[(k0 + j) * 128 + o];
            #pragma unroll
            for (int j = 0; j < 8; ++j)
                #pragma unroll
                for (int i = 0; i < 16; ++i)
                    acc[i] = fmaf(obs_lds[half * 16 + i][k0 + j], w[j], acc[i]);
        }
    } else {
        const unsigned short* Wp = (const unsigned short*)W1;
        float bias = bf2f(((const unsigned short*)b1)[o]);
        #pragma unroll
        for (int i = 0; i < 16; ++i) acc[i] = bias;
        for (int k0 = 0; k0 < 64; k0 += 8) {
            float w[8];
            #pragma unroll
            for (int j = 0; j < 8; ++j) w[j] = bf2f(Wp[(k0 + j) * 128 + o]);
            #pragma unroll
            for (int j = 0; j < 8; ++j)
                #pragma unroll
                for (int i = 0; i < 16; ++i)
                    acc[i] = fmaf(obs_lds[half * 16 + i][k0 + j], w[j], acc[i]);
        }
    }
    #pragma unroll
    for (int i = 0; i < 16; ++i) {
        float th = tanhf(acc[i]);
        int a = half * 16 + i;
        h_f32[(size_t)(abase + a) * 128 + o] = th;
        ht_lds[o][a] = f2bf(th);
    }
    __syncthreads();

    for (int p = 0; p < 16; ++p) {    // 128 feature rows only (no constant rows)
        int n = p * 8 + (t >> 5);
        int a = t & 31;
        hT[(size_t)n * NAG + abase + a] = ht_lds[n][a];
    }
}

// ---------------- Kernel 2: Cp16[ks] = bits-adj @ h  (bf16 MFMA, 8 N-tiles) ----------------
// A from the 8.4 MB bit-matrix (r13/r14, proven); deg column ELIMINATED (popcount in k3)
// -> 8 N-tiles (-11% MFMA and B traffic). BK=128 sub-slices, LDS 34.8 KB, 4 blocks/CU.
__global__ __launch_bounds__(256, 4) void k2_msggemm(
    const uint32_t* __restrict__ bits,        // [8192][256] u32, bit b of word w = col w*32+b
    const unsigned short* __restrict__ hT,    // [128][8192] bf16
    unsigned short* __restrict__ Cp16)        // [NSPLIT][8192][128] fp16
{
    __shared__ __align__(16) unsigned short Blds[128 * LDB2];  // 34,816 B
    const int t = threadIdx.x;
    const int mtile = blockIdx.x & 127;       // 128 M-tiles of 64 rows
    const int ks = blockIdx.x >> 7;           // 8 K-splits of 1024
    const int row0 = mtile * 64;
    const int kbeg = ks * 1024;

    const int wave = t >> 6, lane = t & 63;
    const int fm = lane & 15, quad = lane >> 4;

    floatx4 acc[8];
    #pragma unroll
    for (int i = 0; i < 8; ++i) acc[i] = (floatx4)0.f;

    const int arow = row0 + wave * 16 + fm;
    const uint32_t* aWp = bits + (size_t)arow * 256 + (kbeg >> 5);

    for (int ss = 0; ss < 8; ++ss) {          // 8 sub-slices of 128 k
        if (ss) __syncthreads();              // prior compute done before LDS overwrite
        // stage B[128][128] (L2-hot hT): 2048 16B-chunks over 256 threads = 8 each
        #pragma unroll
        for (int i = 0; i < 8; ++i) {
            int idx = i * 256 + t;
            int row = idx >> 4, ch = idx & 15;
            uint4 v = *reinterpret_cast<const uint4*>(hT + (size_t)row * NAG + kbeg + ss * 128 + ch * 8);
            *reinterpret_cast<uint4*>(&Blds[row * LDB2 + ch * 8]) = v;
        }
        // lane A-bits for this sub-slice: 4 u32 = 16 B
        int4 a0 = *reinterpret_cast<const int4*>(aWp + ss * 4);
        uint32_t aw[4] = {(uint32_t)a0.x, (uint32_t)a0.y, (uint32_t)a0.z, (uint32_t)a0.w};
        __syncthreads();                      // B + bits resident
        #pragma unroll
        for (int kw = 0; kw < 4; ++kw) {      // 4 windows of 32 k
            uint32_t b = (aw[kw] >> (quad * 8)) & 0xFFu;
            union { uint32_t u[4]; short8 s; } af;
            #pragma unroll
            for (int p = 0; p < 4; ++p) {
                uint32_t bb = b >> (2 * p);
                af.u[p] = ((bb & 1u) | ((bb & 2u) << 15)) * 0x3F80u;   // {0,1}->bf16 pair, exact
            }
            #pragma unroll
            for (int j = 0; j < 8; ++j) {
                short8 bf = *reinterpret_cast<const short8*>(&Blds[(j * 16 + fm) * LDB2 + kw * 32 + quad * 8]);
                acc[j] = __builtin_amdgcn_mfma_f32_16x16x32_bf16(af.s, bf, acc[j], 0, 0, 0);
            }
        }
    }

    // epilogue: C/D layout col=lane&15, row=quad*4+reg; fp16 private partial per K-split
    unsigned short* out = Cp16 + (size_t)ks * (NAG * NC);
    #pragma unroll
    for (int j = 0; j < 8; ++j) {
        int col = j * 16 + fm;
        #pragma unroll
        for (int r = 0; r < 4; ++r) {
            int row = row0 + wave * 16 + quad * 4 + r;
            out[(size_t)row * NC + col] = f2h(acc[j][r]);
        }
    }
}

// ---------------- Kernel 3: deg = popcount(bits row); reduce partials; actor MLP ----------------
__global__ __launch_bounds__(256) void k3_actor(
    const float* __restrict__ h_f32,            // [8192][128]
    const unsigned short* __restrict__ Cp16,    // [NSPLIT][8192][128] fp16
    const unsigned long long* __restrict__ bits,// [8192][128] u64
    const void* __restrict__ W1,                // for dtype self-detection
    const void* __restrict__ W2,                // [256][128]
    const void* __restrict__ b2,                // [128]
    const void* __restrict__ W3,                // [128][16]
    const void* __restrict__ b3,                // [16]
    void* __restrict__ out)                     // [8192][16]
{
    __shared__ float4 comb4[8][66];   // [agent][c-quad], c = 0..255
    __shared__ float hid[8][132];
    __shared__ int degp[8][33];
    __shared__ float inv_lds[8];
    const int t = threadIdx.x;
    const int abase = blockIdx.x * 8;
    const bool isf = detect_f32(W1, t);
    const size_t PS = (size_t)NAG * NC;

    {   // deg: 32 threads per agent, 4 u64 popcounts each (exact integer degree)
        int a = t >> 5, j = t & 31;
        const unsigned long long* bp = bits + (size_t)(abase + a) * 128 + j * 4;
        degp[a][j] = __popcll(bp[0]) + __popcll(bp[1]) + __popcll(bp[2]) + __popcll(bp[3]);
    }
    __syncthreads();
    if (t < 8) {
        int d = 0;
        #pragma unroll
        for (int j = 0; j < 32; ++j) d += degp[t][j];
        inv_lds[t] = 1.0f / fmaxf((float)d, 1.0f);
    }
    __syncthreads();

    // stage comb: 8 agents x 64 c-quads = 512 tasks over 256 threads
    #pragma unroll
    for (int jj = 0; jj < 2; ++jj) {
        int idx = jj * 256 + t;
        int a = idx >> 6, q = idx & 63;
        float4 v;
        if (q < 32) {   // h part
            v = *reinterpret_cast<const float4*>(h_f32 + (size_t)(abase + a) * 128 + q * 4);
        } else {        // msg part: sum NSPLIT fp16 partials, scale by 1/deg
            int f = (q - 32) * 4;
            float s0 = 0.f, s1 = 0.f, s2 = 0.f, s3 = 0.f;
            #pragma unroll
            for (int s = 0; s < NSPLIT; ++s) {
                ushort4 p = *reinterpret_cast<const ushort4*>(Cp16 + s * PS + (size_t)(abase + a) * NC + f);
                s0 += h2f(p.x); s1 += h2f(p.y); s2 += h2f(p.z); s3 += h2f(p.w);
            }
            float sc = inv_lds[a];
            v = make_float4(s0 * sc, s1 * sc, s2 * sc, s3 * sc);
        }
        comb4[a][q] = v;
    }
    __syncthreads();

    const int o = t & 127, half = t >> 7;   // 4 agents per half
    float acc[4];
    if (isf) {
        const float* Wp = (const float*)W2;
        float bias = ((const float*)b2)[o];
        #pragma unroll
        for (int i = 0; i < 4; ++i) acc[i] = bias;
        for (int cq = 0; cq < 64; ++cq) {
            float w0 = Wp[(cq * 4 + 0) * 128 + o];
            float w1 = Wp[(cq * 4 + 1) * 128 + o];
            float w2 = Wp[(cq * 4 + 2) * 128 + o];
            float w3 = Wp[(cq * 4 + 3) * 128 + o];
            #pragma unroll
            for (int i = 0; i < 4; ++i) {
                float4 v = comb4[half * 4 + i][cq];
                acc[i] = fmaf(v.x, w0, acc[i]);
                acc[i] = fmaf(v.y, w1, acc[i]);
                acc[i] = fmaf(v.z, w2, acc[i]);
                acc[i] = fmaf(v.w, w3, acc[i]);
            }
        }
    } else {
        const unsigned short* Wp = (const unsigned short*)W2;
        float bias = bf2f(((const unsigned short*)b2)[o]);
        #pragma unroll
        for (int i = 0; i < 4; ++i) acc[i] = bias;
        for (int cq = 0; cq < 64; ++cq) {
            float w0 = bf2f(Wp[(cq * 4 + 0) * 128 + o]);
            float w1 = bf2f(Wp[(cq * 4 + 1) * 128 + o]);
            float w2 = bf2f(Wp[(cq * 4 + 2) * 128 + o]);
            float w3 = bf2f(Wp[(cq * 4 + 3) * 128 + o]);
            #pragma unroll
            for (int i = 0; i < 4; ++i) {
                float4 v = comb4[half * 4 + i][cq];
                acc[i] = fmaf(v.x, w0, acc[i]);
                acc[i] = fmaf(v.y, w1, acc[i]);
                acc[i] = fmaf(v.z, w2, acc[i]);
                acc[i] = fmaf(v.w, w3, acc[i]);
            }
        }
    }
    #pragma unroll
    for (int i = 0; i < 4; ++i)
        hid[half * 4 + i][o] = tanhf(acc[i]);
    __syncthreads();

    if (t < 128) {   // 8 agents x 16 outputs
        const int q = t & 15, ar = t >> 4;
        float l;
        if (isf) {
            const float* Wp = (const float*)W3;
            l = ((const float*)b3)[q];
            #pragma unroll 4
            for (int oo = 0; oo < 128; ++oo)
                l = fmaf(hid[ar][oo], Wp[oo * 16 + q], l);
        } else {
            const unsigned short* Wp = (const unsigned short*)W3;
            l = bf2f(((const unsigned short*)b3)[q]);
            #pragma unroll 4
            for (int oo = 0; oo < 128; ++oo)
                l = fmaf(hid[ar][oo], bf2f(Wp[oo * 16 + q]), l);
        }
        size_t i0 = (size_t)(abase + ar) * 16 + q;
        if (isf) ((float*)out)[i0] = l;
        else     ((unsigned short*)out)[i0] = f2bf(l);
    }
}

extern "C" void kernel_launch(void* const* d_in, const int* in_sizes, int n_in,
                              void* d_out, int out_size, void* d_ws, size_t ws_size,
                              hipStream_t stream) {
    const void* obs = d_in[0];
    const int*  adj = (const int*)d_in[1];
    const void* W1  = d_in[2];
    const void* b1  = d_in[3];
    const void* W2  = d_in[4];
    const void* b2  = d_in[5];
    const void* W3  = d_in[6];
    const void* b3  = d_in[7];

    char* ws = (char*)d_ws;
    unsigned short* hT   = (unsigned short*)(ws);                    // 128*8192*2   =  2,097,152 B
    float*          h_f32= (float*)(ws + 2097152);                   // 8192*128*4   =  4,194,304 B
    unsigned short* Cp16 = (unsigned short*)(ws + 6291456);          // 8*8192*128*2 = 16,777,216 B
    unsigned long long* bits = (unsigned long long*)(ws + 23068672); // 8192*8192/8  =  8,388,608 B
                                                                     // total ~31.5 MB

    hipLaunchKernelGGL(kA_pack_encode, dim3(2304), dim3(256), 0, stream,
                       adj, bits, obs, W1, b1, h_f32, hT);
    hipLaunchKernelGGL(k2_msggemm, dim3(1024), dim3(256), 0, stream,
                       (const uint32_t*)bits, hT, Cp16);
    hipLaunchKernelGGL(k3_actor, dim3(1024), dim3(256), 0, stream,
                       h_f32, Cp16, bits, W1, W2, b2, W3, b3, d_out);
}